// Round 1
// baseline (282.453 us; speedup 1.0000x reference)
//
#include <hip/hip_runtime.h>

// Weighted BCE mean-reduction, N = 33,554,432 fp32 + int32 labels.
// Memory-bound: 256 MB read @ ~6.3 TB/s achievable => ~41 us floor.
// Strategy: float4/int4 vector loads, branchless single-log per element,
// wave64 shuffle reduce -> LDS -> one atomicAdd per block into d_out.

#define WBCE_BLOCK 256
#define WBCE_GRID  2048   // 256 CUs x 8 blocks; 16 float4 iters/thread at N=32M

__global__ __launch_bounds__(WBCE_BLOCK) void weightedBCE_75582834475452_kernel(
    const float4* __restrict__ x4,
    const int4*   __restrict__ y4,
    const float*  __restrict__ weights,
    float*        __restrict__ out,
    int n4, int n, float inv_n)
{
    const float w0 = weights[0];
    const float w1 = weights[1];

    float acc = 0.0f;  // accumulates w * log(t); final loss = -acc

    const int tid    = blockIdx.x * WBCE_BLOCK + threadIdx.x;
    const int stride = WBCE_GRID * WBCE_BLOCK;

    for (int i = tid; i < n4; i += stride) {
        const float4 xv = x4[i];
        const int4   yv = y4[i];

        // branchless: t = y==1 ? x : 1-x ; w = y==1 ? w1 : w0 ; loss = -w*log(t)
        float t0 = (yv.x == 1) ? xv.x : (1.0f - xv.x);
        float t1 = (yv.y == 1) ? xv.y : (1.0f - xv.y);
        float t2 = (yv.z == 1) ? xv.z : (1.0f - xv.z);
        float t3 = (yv.w == 1) ? xv.w : (1.0f - xv.w);
        float wa = (yv.x == 1) ? w1 : w0;
        float wb = (yv.y == 1) ? w1 : w0;
        float wc = (yv.z == 1) ? w1 : w0;
        float wd = (yv.w == 1) ? w1 : w0;

        acc += wa * __logf(t0);
        acc += wb * __logf(t1);
        acc += wc * __logf(t2);
        acc += wd * __logf(t3);
    }

    // scalar tail (N is divisible by 4 in this problem, but stay safe)
    const float* xs = (const float*)x4;
    const int*   ys = (const int*)y4;
    for (int i = n4 * 4 + tid; i < n; i += stride) {
        float xv = xs[i];
        int   yv = ys[i];
        float t = (yv == 1) ? xv : (1.0f - xv);
        float w = (yv == 1) ? w1 : w0;
        acc += w * __logf(t);
    }

    // wave-64 butterfly reduce
    #pragma unroll
    for (int off = 32; off > 0; off >>= 1)
        acc += __shfl_down(acc, off, 64);

    __shared__ float smem[WBCE_BLOCK / 64];
    const int lane = threadIdx.x & 63;
    const int wave = threadIdx.x >> 6;
    if (lane == 0) smem[wave] = acc;
    __syncthreads();

    if (threadIdx.x == 0) {
        float total = 0.0f;
        #pragma unroll
        for (int w = 0; w < WBCE_BLOCK / 64; ++w) total += smem[w];
        // loss = -sum(w*log t); pre-scale by 1/N so d_out holds the mean
        atomicAdd(out, -total * inv_n);
    }
}

extern "C" void kernel_launch(void* const* d_in, const int* in_sizes, int n_in,
                              void* d_out, int out_size, void* d_ws, size_t ws_size,
                              hipStream_t stream) {
    const float* x = (const float*)d_in[0];
    const int*   y = (const int*)d_in[1];
    const float* w = (const float*)d_in[2];
    float* out = (float*)d_out;
    const int n  = in_sizes[0];
    const int n4 = n >> 2;

    // d_out is poisoned to 0xAA before every timed replay — zero it on-stream
    // (hipMemsetAsync is graph-capture safe).
    hipMemsetAsync(out, 0, sizeof(float), stream);

    weightedBCE_75582834475452_kernel<<<WBCE_GRID, WBCE_BLOCK, 0, stream>>>(
        (const float4*)x, (const int4*)y, w, out, n4, n, 1.0f / (float)n);
}

// Round 2
// 278.878 us; speedup vs baseline: 1.0128x; 1.0128x over previous
//
#include <hip/hip_runtime.h>

// Weighted BCE mean-reduction, N = 33,554,432 fp32 + int32 labels.
// Memory-bound in theory (256 MB read => ~41 us @ 6.3 TB/s), but R1 showed
// latency-bound reality: rolled loop = only 2 loads in flight per wave
// (VGPR=16, VALUBusy 15%, 105 us). Fix: specialize the exact-size case and
// issue 4 independent float4+int4 load pairs per unrolled group => 8 loads
// (128 B) outstanding per wave before the first s_waitcnt.

#define WBCE_BLOCK 256
#define WBCE_GRID  2048            // 256 CUs x 8 blocks/CU (exactly fills at 32 waves/CU)
#define WBCE_STRIDE (WBCE_GRID * WBCE_BLOCK)   // 524288 threads
#define WBCE_ITERS 16              // n4 / WBCE_STRIDE when N = 33554432

__device__ __forceinline__ float wbce_elem(float x, int y, float w0, float w1) {
    float t = (y == 1) ? x : (1.0f - x);
    float w = (y == 1) ? w1 : w0;
    return w * __logf(t);
}

__device__ __forceinline__ float wbce_quad(float4 xv, int4 yv, float w0, float w1) {
    float a = wbce_elem(xv.x, yv.x, w0, w1);
    float b = wbce_elem(xv.y, yv.y, w0, w1);
    float c = wbce_elem(xv.z, yv.z, w0, w1);
    float d = wbce_elem(xv.w, yv.w, w0, w1);
    return (a + b) + (c + d);
}

__global__ __launch_bounds__(WBCE_BLOCK) void weightedBCE_75582834475452_kernel(
    const float4* __restrict__ x4,
    const int4*   __restrict__ y4,
    const float*  __restrict__ weights,
    float*        __restrict__ out,
    int n4, int n, float inv_n)
{
    const float w0 = weights[0];
    const float w1 = weights[1];

    float acc = 0.0f;  // accumulates w * log(t); final loss = -acc
    const int tid = blockIdx.x * WBCE_BLOCK + threadIdx.x;

    if (n4 == WBCE_ITERS * WBCE_STRIDE) {
        // Specialized path: 16 iters/thread, grouped 4x4 for memory-level
        // parallelism. Each group issues 4 independent x4/y4 load pairs
        // before any consumption.
        #pragma unroll
        for (int g = 0; g < WBCE_ITERS / 4; ++g) {
            const int base = tid + g * 4 * WBCE_STRIDE;
            float4 xa = x4[base + 0 * WBCE_STRIDE];
            float4 xb = x4[base + 1 * WBCE_STRIDE];
            float4 xc = x4[base + 2 * WBCE_STRIDE];
            float4 xd = x4[base + 3 * WBCE_STRIDE];
            int4   ya = y4[base + 0 * WBCE_STRIDE];
            int4   yb = y4[base + 1 * WBCE_STRIDE];
            int4   yc = y4[base + 2 * WBCE_STRIDE];
            int4   yd = y4[base + 3 * WBCE_STRIDE];
            acc += wbce_quad(xa, ya, w0, w1);
            acc += wbce_quad(xb, yb, w0, w1);
            acc += wbce_quad(xc, yc, w0, w1);
            acc += wbce_quad(xd, yd, w0, w1);
        }
    } else {
        // Generic fallback (grid-stride) — keeps correctness for any N.
        for (int i = tid; i < n4; i += WBCE_STRIDE) {
            acc += wbce_quad(x4[i], y4[i], w0, w1);
        }
        const float* xs = (const float*)x4;
        const int*   ys = (const int*)y4;
        for (int i = n4 * 4 + tid; i < n; i += WBCE_STRIDE) {
            acc += wbce_elem(xs[i], ys[i], w0, w1);
        }
    }

    // wave-64 butterfly reduce
    #pragma unroll
    for (int off = 32; off > 0; off >>= 1)
        acc += __shfl_down(acc, off, 64);

    __shared__ float smem[WBCE_BLOCK / 64];
    const int lane = threadIdx.x & 63;
    const int wave = threadIdx.x >> 6;
    if (lane == 0) smem[wave] = acc;
    __syncthreads();

    if (threadIdx.x == 0) {
        float total = 0.0f;
        #pragma unroll
        for (int w = 0; w < WBCE_BLOCK / 64; ++w) total += smem[w];
        // loss = -sum(w*log t); pre-scale by 1/N so d_out holds the mean
        atomicAdd(out, -total * inv_n);
    }
}

extern "C" void kernel_launch(void* const* d_in, const int* in_sizes, int n_in,
                              void* d_out, int out_size, void* d_ws, size_t ws_size,
                              hipStream_t stream) {
    const float* x = (const float*)d_in[0];
    const int*   y = (const int*)d_in[1];
    const float* w = (const float*)d_in[2];
    float* out = (float*)d_out;
    const int n  = in_sizes[0];
    const int n4 = n >> 2;

    // d_out is poisoned to 0xAA before every timed replay — zero it on-stream
    // (hipMemsetAsync is graph-capture safe).
    hipMemsetAsync(out, 0, sizeof(float), stream);

    weightedBCE_75582834475452_kernel<<<WBCE_GRID, WBCE_BLOCK, 0, stream>>>(
        (const float4*)x, (const int4*)y, w, out, n4, n, 1.0f / (float)n);
}

// Round 4
// 257.725 us; speedup vs baseline: 1.0959x; 1.0821x over previous
//
#include <hip/hip_runtime.h>

// Weighted BCE mean-reduction, N = 33,554,432 fp32 + int32 labels.
// R1 (rolled) and R2 (unrolled, 4x MLP attempt) both land at ~106 us =
// 256 MB / 2.4 TB/s effective read, independent of code structure, with
// VALUBusy 15% / HBM 16% / occupancy 70%. Theory: per-CU L1/TCP fill path
// caps streaming reads. R3/R4: nontemporal loads (`nt` flag) so streaming
// data doesn't allocate/probe L1. R3 failed to compile —
// __builtin_nontemporal_load needs native Clang vector types, not
// HIP_vector_type structs — R4 uses ext_vector_type(4) typedefs.

#define WBCE_BLOCK 256
#define WBCE_GRID  2048            // 256 CUs x 8 blocks/CU = 32 waves/CU (max)
#define WBCE_STRIDE (WBCE_GRID * WBCE_BLOCK)   // 524288 threads
#define WBCE_ITERS 16              // n4 / WBCE_STRIDE when N = 33554432

typedef float fx4 __attribute__((ext_vector_type(4)));
typedef int   ix4 __attribute__((ext_vector_type(4)));

__device__ __forceinline__ float wbce_elem(float x, int y, float lw0, float lw1) {
    // returns w * ln(t) with lw = w*ln2 pre-folded: lw_sel * log2(t)
    float t  = (y == 1) ? x : (1.0f - x);
    float lw = (y == 1) ? lw1 : lw0;
    return lw * __log2f(t);
}

__device__ __forceinline__ float wbce_quad(fx4 xv, ix4 yv, float lw0, float lw1) {
    float a = wbce_elem(xv.x, yv.x, lw0, lw1);
    float b = wbce_elem(xv.y, yv.y, lw0, lw1);
    float c = wbce_elem(xv.z, yv.z, lw0, lw1);
    float d = wbce_elem(xv.w, yv.w, lw0, lw1);
    return (a + b) + (c + d);
}

__global__ __launch_bounds__(WBCE_BLOCK) void weightedBCE_75582834475452_kernel(
    const fx4* __restrict__ x4,
    const ix4* __restrict__ y4,
    const float* __restrict__ weights,
    float*       __restrict__ out,
    int n4, int n, float inv_n)
{
    const float ln2 = 0.69314718055994530942f;
    const float lw0 = weights[0] * ln2;
    const float lw1 = weights[1] * ln2;

    float acc = 0.0f;  // accumulates w * ln(t); final loss = -acc
    const int tid = blockIdx.x * WBCE_BLOCK + threadIdx.x;

    if (n4 == WBCE_ITERS * WBCE_STRIDE) {
        #pragma unroll
        for (int g = 0; g < WBCE_ITERS / 2; ++g) {
            const int base = tid + g * 2 * WBCE_STRIDE;
            fx4 xa = __builtin_nontemporal_load(&x4[base + 0 * WBCE_STRIDE]);
            fx4 xb = __builtin_nontemporal_load(&x4[base + 1 * WBCE_STRIDE]);
            ix4 ya = __builtin_nontemporal_load(&y4[base + 0 * WBCE_STRIDE]);
            ix4 yb = __builtin_nontemporal_load(&y4[base + 1 * WBCE_STRIDE]);
            acc += wbce_quad(xa, ya, lw0, lw1);
            acc += wbce_quad(xb, yb, lw0, lw1);
        }
    } else {
        // Generic fallback (grid-stride) — correctness for any N.
        for (int i = tid; i < n4; i += WBCE_STRIDE) {
            fx4 xv = __builtin_nontemporal_load(&x4[i]);
            ix4 yv = __builtin_nontemporal_load(&y4[i]);
            acc += wbce_quad(xv, yv, lw0, lw1);
        }
        const float* xs = (const float*)x4;
        const int*   ys = (const int*)y4;
        for (int i = n4 * 4 + tid; i < n; i += WBCE_STRIDE) {
            acc += wbce_elem(xs[i], ys[i], lw0, lw1);
        }
    }

    // wave-64 butterfly reduce
    #pragma unroll
    for (int off = 32; off > 0; off >>= 1)
        acc += __shfl_down(acc, off, 64);

    __shared__ float smem[WBCE_BLOCK / 64];
    const int lane = threadIdx.x & 63;
    const int wave = threadIdx.x >> 6;
    if (lane == 0) smem[wave] = acc;
    __syncthreads();

    if (threadIdx.x == 0) {
        float total = 0.0f;
        #pragma unroll
        for (int w = 0; w < WBCE_BLOCK / 64; ++w) total += smem[w];
        // loss = -sum(w*ln t); pre-scale by 1/N so d_out holds the mean
        atomicAdd(out, -total * inv_n);
    }
}

extern "C" void kernel_launch(void* const* d_in, const int* in_sizes, int n_in,
                              void* d_out, int out_size, void* d_ws, size_t ws_size,
                              hipStream_t stream) {
    const float* x = (const float*)d_in[0];
    const int*   y = (const int*)d_in[1];
    const float* w = (const float*)d_in[2];
    float* out = (float*)d_out;
    const int n  = in_sizes[0];
    const int n4 = n >> 2;

    // d_out is poisoned to 0xAA before every timed replay — zero it on-stream
    // (hipMemsetAsync is graph-capture safe).
    (void)hipMemsetAsync(out, 0, sizeof(float), stream);

    weightedBCE_75582834475452_kernel<<<WBCE_GRID, WBCE_BLOCK, 0, stream>>>(
        (const fx4*)x, (const ix4*)y, w, out, n4, n, 1.0f / (float)n);
}

// Round 5
// 257.725 us; speedup vs baseline: 1.0959x; 1.0000x over previous
//
#include <hip/hip_runtime.h>

// Weighted BCE mean-reduction, N = 33,554,432 fp32 + int32 labels.
// History: R1/R2 ~106 us (2.4 TB/s, L1/TCP fill-path cap, code-structure
// invariant). R4: nontemporal loads bypass L1 -> kernel <= ~77 us (fell out
// of top-5 dispatches; harness fills at 78 us / 6.9 TB/s write are now the
// longest). R5: widen MLP to 4 load-pairs (8 nt loads, 128 B/lane in
// flight) per group — with L1 bypassed, full HBM latency (~900 cyc) makes
// per-wave outstanding-load count the residual limiter.

#define WBCE_BLOCK 256
#define WBCE_GRID  2048            // 256 CUs x 8 blocks/CU = 32 waves/CU (max)
#define WBCE_STRIDE (WBCE_GRID * WBCE_BLOCK)   // 524288 threads
#define WBCE_ITERS 16              // n4 / WBCE_STRIDE when N = 33554432

typedef float fx4 __attribute__((ext_vector_type(4)));
typedef int   ix4 __attribute__((ext_vector_type(4)));

__device__ __forceinline__ float wbce_elem(float x, int y, float lw0, float lw1) {
    // returns w * ln(t) with lw = w*ln2 pre-folded: lw_sel * log2(t)
    float t  = (y == 1) ? x : (1.0f - x);
    float lw = (y == 1) ? lw1 : lw0;
    return lw * __log2f(t);
}

__device__ __forceinline__ float wbce_quad(fx4 xv, ix4 yv, float lw0, float lw1) {
    float a = wbce_elem(xv.x, yv.x, lw0, lw1);
    float b = wbce_elem(xv.y, yv.y, lw0, lw1);
    float c = wbce_elem(xv.z, yv.z, lw0, lw1);
    float d = wbce_elem(xv.w, yv.w, lw0, lw1);
    return (a + b) + (c + d);
}

__global__ __launch_bounds__(WBCE_BLOCK) void weightedBCE_75582834475452_kernel(
    const fx4* __restrict__ x4,
    const ix4* __restrict__ y4,
    const float* __restrict__ weights,
    float*       __restrict__ out,
    int n4, int n, float inv_n)
{
    const float ln2 = 0.69314718055994530942f;
    const float lw0 = weights[0] * ln2;
    const float lw1 = weights[1] * ln2;

    float acc = 0.0f;  // accumulates w * ln(t); final loss = -acc
    const int tid = blockIdx.x * WBCE_BLOCK + threadIdx.x;

    if (n4 == WBCE_ITERS * WBCE_STRIDE) {
        // 4 groups x 4 pairs: 8 nt loads (128 B/lane) in flight per group.
        // Payload = 32 VGPRs; total stays <= 64 so 8 waves/SIMD hold.
        #pragma unroll
        for (int g = 0; g < WBCE_ITERS / 4; ++g) {
            const int base = tid + g * 4 * WBCE_STRIDE;
            fx4 xa = __builtin_nontemporal_load(&x4[base + 0 * WBCE_STRIDE]);
            fx4 xb = __builtin_nontemporal_load(&x4[base + 1 * WBCE_STRIDE]);
            fx4 xc = __builtin_nontemporal_load(&x4[base + 2 * WBCE_STRIDE]);
            fx4 xd = __builtin_nontemporal_load(&x4[base + 3 * WBCE_STRIDE]);
            ix4 ya = __builtin_nontemporal_load(&y4[base + 0 * WBCE_STRIDE]);
            ix4 yb = __builtin_nontemporal_load(&y4[base + 1 * WBCE_STRIDE]);
            ix4 yc = __builtin_nontemporal_load(&y4[base + 2 * WBCE_STRIDE]);
            ix4 yd = __builtin_nontemporal_load(&y4[base + 3 * WBCE_STRIDE]);
            acc += wbce_quad(xa, ya, lw0, lw1);
            acc += wbce_quad(xb, yb, lw0, lw1);
            acc += wbce_quad(xc, yc, lw0, lw1);
            acc += wbce_quad(xd, yd, lw0, lw1);
        }
    } else {
        // Generic fallback (grid-stride) — correctness for any N.
        for (int i = tid; i < n4; i += WBCE_STRIDE) {
            fx4 xv = __builtin_nontemporal_load(&x4[i]);
            ix4 yv = __builtin_nontemporal_load(&y4[i]);
            acc += wbce_quad(xv, yv, lw0, lw1);
        }
        const float* xs = (const float*)x4;
        const int*   ys = (const int*)y4;
        for (int i = n4 * 4 + tid; i < n; i += WBCE_STRIDE) {
            acc += wbce_elem(xs[i], ys[i], lw0, lw1);
        }
    }

    // wave-64 butterfly reduce
    #pragma unroll
    for (int off = 32; off > 0; off >>= 1)
        acc += __shfl_down(acc, off, 64);

    __shared__ float smem[WBCE_BLOCK / 64];
    const int lane = threadIdx.x & 63;
    const int wave = threadIdx.x >> 6;
    if (lane == 0) smem[wave] = acc;
    __syncthreads();

    if (threadIdx.x == 0) {
        float total = 0.0f;
        #pragma unroll
        for (int w = 0; w < WBCE_BLOCK / 64; ++w) total += smem[w];
        // loss = -sum(w*ln t); pre-scale by 1/N so d_out holds the mean
        atomicAdd(out, -total * inv_n);
    }
}

extern "C" void kernel_launch(void* const* d_in, const int* in_sizes, int n_in,
                              void* d_out, int out_size, void* d_ws, size_t ws_size,
                              hipStream_t stream) {
    const float* x = (const float*)d_in[0];
    const int*   y = (const int*)d_in[1];
    const float* w = (const float*)d_in[2];
    float* out = (float*)d_out;
    const int n  = in_sizes[0];
    const int n4 = n >> 2;

    // d_out is poisoned to 0xAA before every timed replay — zero it on-stream
    // (hipMemsetAsync is graph-capture safe).
    (void)hipMemsetAsync(out, 0, sizeof(float), stream);

    weightedBCE_75582834475452_kernel<<<WBCE_GRID, WBCE_BLOCK, 0, stream>>>(
        (const fx4*)x, (const ix4*)y, w, out, n4, n, 1.0f / (float)n);
}